// Round 9
// baseline (261.869 us; speedup 1.0000x reference)
//
#include <hip/hip_runtime.h>

typedef _Float16 f16;
typedef __fp16 fp16x2 __attribute__((ext_vector_type(2)));
typedef _Float16 half4 __attribute__((ext_vector_type(4)));
typedef _Float16 half8 __attribute__((ext_vector_type(8)));
typedef float floatx16 __attribute__((ext_vector_type(16)));

#define FSTR 44     // r-dim per field in f16 (42 used; reads of r44..47 hit next field / pad, coeff g=0)
#define XSTR 180    // per-x stride f16: 4*44 + 4 pad = 360 B; 90 dwords (=26 mod 32) -> conflict-free
#define WTOT (32 * XSTR)          // 5760 f16 = 11520 B per wave; 2 waves = 23040 B

union H8 { half8 v; half4 h[2]; fp16x2 p[4]; unsigned u[4]; };
union H4 { half4 v; fp16x2 p[2]; };

// Fused SSIM via MFMA, H-pass then V-pass, per-wave private T^T in LDS.
// BYTE-EXACT ROUND-3 BODY (verified best: 53.5 us kernel, WRITE 384 KB = no
// spill). ONLY the tail differs: waves atomicAdd(-vsum*invN) straight into
// out[0] (block0/wave0 folds in the +1.0), so the finalize dispatch and the
// workspace are GONE: 2 enqueued ops instead of 3. Measured e2e - kernel =
// 78-93 us of fixed per-call overhead across all rounds -- dispatch count is
// the only untried lever; kernel-side r4-r8 variants all spilled or regressed.
// MEASURED CONSTRAINTS (each cost a round, do not violate):
//  - EXACT r3 body/ordering. r8 accR-reuse+sched_barrier: 21.9 MB spill.
//    r6 band2-late: 24 MB spill. r4 reg-resident pass2 / r5 2-tile loop:
//    28-65 MB spill (compile-time loops fully unroll at -O3, merge lifetimes).
//  - NO XCD swizzle: r7 isolated it: FETCH 92->49 MB but dur 53.5->62 us
//    (latency-bound; same-row concentration costs more than locality buys).
//  - launch_bounds(128,3): (128,4) caps regs at 128 -> 9.6 MB spill (r1-r2).
//  - No fences in tail: agent-scope fence = L2 writeback on gfx950 (8x, r1).
//  - m=1 source rows deduped at oy+36: T rows >=42 multiply g=0.
// No clip: |clip(x)-x| <= 1e-6, ~500x below fp16-RTZ noise already present.

__device__ __forceinline__ void load_tile(
    const float* __restrict__ img1, const float* __restrict__ img2, size_t base,
    int row, int rowcap, int x0, int q, float4 ra[3][2], float4 rb[3][2], unsigned mk[3])
{
    int rowc = min(max(min(row, rowcap), 0), 511);   // load address (deduped)
    bool rok = (row >= 0) && (row <= 511);           // mask from wanted row
    const float* r1 = img1 + base + (size_t)rowc * 512;
    const float* r2 = img2 + base + (size_t)rowc * 512;
    #pragma unroll
    for (int ch = 0; ch < 3; ++ch) {
        int cb  = x0 - 8 + 16 * ch + 8 * q;      // 8-col chunk, 32B aligned
        int cbc = min(max(cb, 0), 504);
        mk[ch] = (cb == cbc && rok) ? 0xFFFFFFFFu : 0u;
        ra[ch][0] = *(const float4*)(r1 + cbc);
        ra[ch][1] = *(const float4*)(r1 + cbc + 4);
        rb[ch][0] = *(const float4*)(r2 + cbc);
        rb[ch][1] = *(const float4*)(r2 + cbc + 4);
    }
}

__device__ __forceinline__ void compute_acct(
    const float4 ra[3][2], const float4 rb[3][2], const unsigned mk[3],
    const half8 band1[3], floatx16 acc[4])
{
    #pragma unroll
    for (int ch = 0; ch < 3; ++ch) {
        H8 F0, F1, F2, F3;
        #pragma unroll
        for (int h = 0; h < 2; ++h) {
            const float as[4] = {ra[ch][h].x, ra[ch][h].y, ra[ch][h].z, ra[ch][h].w};
            const float bs[4] = {rb[ch][h].x, rb[ch][h].y, rb[ch][h].z, rb[ch][h].w};
            #pragma unroll
            for (int t = 0; t < 2; ++t) {
                float a0 = as[2*t], a1 = as[2*t+1];
                float b0 = bs[2*t], b1 = bs[2*t+1];
                int jj = 2 * h + t;
                F0.p[jj] = __builtin_amdgcn_cvt_pkrtz(a0, a1);
                F1.p[jj] = __builtin_amdgcn_cvt_pkrtz(b0, b1);
                F2.p[jj] = __builtin_amdgcn_cvt_pkrtz(a0*a0 + b0*b0, a1*a1 + b1*b1);
                F3.p[jj] = __builtin_amdgcn_cvt_pkrtz(a0*b0, a1*b1);
            }
        }
        // OOB mask (row clamp / col chunk) as packed AND: {0,1} multiply -> bitmask
        unsigned m = mk[ch];
        #pragma unroll
        for (int i = 0; i < 4; ++i) { F0.u[i] &= m; F1.u[i] &= m; F2.u[i] &= m; F3.u[i] &= m; }
        acc[0] = __builtin_amdgcn_mfma_f32_32x32x16_f16(F0.v, band1[ch], acc[0], 0, 0, 0);
        acc[1] = __builtin_amdgcn_mfma_f32_32x32x16_f16(F1.v, band1[ch], acc[1], 0, 0, 0);
        acc[2] = __builtin_amdgcn_mfma_f32_32x32x16_f16(F2.v, band1[ch], acc[2], 0, 0, 0);
        acc[3] = __builtin_amdgcn_mfma_f32_32x32x16_f16(F3.v, band1[ch], acc[3], 0, 0, 0);
    }
}

// write T^T fields [FLO,FHI) of m-tile MT; D: row r = 8s+4q(+32*MT), col x = ln.
// MT==1,s==1,q==1 would be r44..47 (overlaps next field's r0..3) -> exec-masked off;
// those slots are only ever read against g=0.
template<int MT, int FLO, int FHI>
__device__ __forceinline__ void write_T(f16* tx, int q, const floatx16 acc[4])
{
    #pragma unroll
    for (int f = FLO; f < FHI; ++f) {
        #pragma unroll
        for (int s = 0; s < (MT == 0 ? 4 : 2); ++s) {
            const int r0 = 8 * s + 4 * q + 32 * MT;
            H4 h4;
            h4.p[0] = __builtin_amdgcn_cvt_pkrtz(acc[f][4*s],   acc[f][4*s+1]);
            h4.p[1] = __builtin_amdgcn_cvt_pkrtz(acc[f][4*s+2], acc[f][4*s+3]);
            if (MT == 1 && s == 1) {
                if (q == 0) *(half4*)(tx + f * FSTR + r0) = h4.v;
            } else {
                *(half4*)(tx + f * FSTR + r0) = h4.v;
            }
        }
    }
}

__global__ __launch_bounds__(128, 3) void ssim_kernel(
    const float* __restrict__ img1, const float* __restrict__ img2,
    const float* __restrict__ window, float* __restrict__ out)
{
    __shared__ __align__(16) f16 smem[2 * WTOT];

    const int tid  = threadIdx.x;
    const int lane = tid & 63;
    const int wv   = tid >> 6;
    const int q    = lane >> 5;
    const int ln   = lane & 31;

    const int bz = blockIdx.z;
    const int c  = bz % 3;
    const int x0 = blockIdx.x * 64 + 32 * wv;
    const int oy = blockIdx.y * 32;
    const size_t base = (size_t)bz * (512 * 512);

    f16* Tw = smem + wv * WTOT;                    // this wave's T^T [x32][f4][r44] (+4 pad)

    // ---- issue ALL 24 float4 loads up front (both m-tiles in flight) ----
    float4 ra[3][2], rb[3][2]; unsigned mk[3];
    load_tile(img1, img2, base, oy - 5 + ln, 511, x0, q, ra, rb, mk);
    float4 ra1[3][2], rb1[3][2]; unsigned mk1[3];
    load_tile(img1, img2, base, oy + 27 + ln, oy + 36, x0, q, ra1, rb1, mk1);

    // per-wave 1-D gaussian: lane t<11 holds g[t] = sum_j w2d[t][j]
    float gv = 0.f;
    if (lane < 11) {
        const float* w2 = window + c * 121 + lane * 11;
        #pragma unroll
        for (int j = 0; j < 11; ++j) gv += w2[j];
    }

    // zero each x-slot's 4-f16 pad (read x g=0 by pass2; must be finite)
    if (lane < 32) {
        half4 z4 = {};
        *(half4*)(Tw + lane * XSTR + 176) = z4;
    }

    // bands from ONE shared 11-shuffle gather per ch:
    //   band1[j] = g[16ch+8q-ln-3 + j], band2[j] = band-gather[j+3]
    half8 band1[3], band2[3];
    #pragma unroll
    for (int ch = 0; ch < 3; ++ch) {
        int ib = 16 * ch + 8 * q - ln - 3;
        float gg[11];
        #pragma unroll
        for (int t = 0; t < 11; ++t) gg[t] = __shfl(gv, (ib + t) & 63, 64);
        H8 t1, t2;
        #pragma unroll
        for (int jj = 0; jj < 4; ++jj) {
            fp16x2 p1 = { (__fp16)gg[2*jj],     (__fp16)gg[2*jj + 1] };
            fp16x2 p2 = { (__fp16)gg[2*jj + 3], (__fp16)gg[2*jj + 4] };
            t1.p[jj] = p1; t2.p[jj] = p2;
        }
        band1[ch] = t1.v; band2[ch] = t2.v;
    }

    // ---- pass 1, m=0 (rows oy-5+ln) ----
    floatx16 accT[4] = {};
    compute_acct(ra, rb, mk, band1, accT);
    f16* tx = Tw + ln * XSTR;
    write_T<0, 0, 4>(tx, q, accT);

    // ---- pass 1, m=1 (rows oy+27+ln, deduped source; only r32..43 stored) ----
    floatx16 accU[4] = {};
    compute_acct(ra1, rb1, mk1, band1, accU);
    write_T<1, 0, 4>(tx, q, accU);

    // ---- pass 2 (vertical): A-frags = two aligned b64 LDS reads per (ch,f) ----
    // No barrier needed: Tw is wave-private, DS ops ordered in-wave via lgkmcnt.
    floatx16 accH[4] = {};
    #pragma unroll
    for (int ch = 0; ch < 3; ++ch) {
        const f16* tb = Tw + ln * XSTR + 16 * ch + 8 * q;
        #pragma unroll
        for (int f = 0; f < 4; ++f) {
            H8 af;
            af.h[0] = *(const half4*)(tb + f * FSTR);
            af.h[1] = *(const half4*)(tb + f * FSTR + 4);
            accH[f] = __builtin_amdgcn_mfma_f32_32x32x16_f16(af.v, band2[ch], accH[f], 0, 0, 0);
        }
    }

    // ---- epilogue: all 16 outputs per lane valid (exact tiling) ----
    float vsum = 0.f;
    const float C1 = 1e-4f, C2 = 9e-4f;
    #pragma unroll
    for (int r = 0; r < 16; ++r) {
        float mu1 = accH[0][r], mu2 = accH[1][r];
        float S = accH[2][r], E12 = accH[3][r];
        float mu11 = mu1 * mu1, mu22 = mu2 * mu2, mu12 = mu1 * mu2;
        float num = (2.f * mu12 + C1) * (2.f * (E12 - mu12) + C2);
        float den = (mu11 + mu22 + C1) * (S - mu11 - mu22 + C2);
        vsum += num * __builtin_amdgcn_rcpf(den);
    }

    // wave reduce -> ONE fire-and-forget atomic per wave, straight into out[0]:
    // out = 1 - sum*invN, with the +1.0 folded into block(0,0,0)/wave0's add.
    // out[0] starts at 0.0 via 4-byte memset (no workspace, no finalize pass).
    #pragma unroll
    for (int off = 32; off > 0; off >>= 1) vsum += __shfl_down(vsum, off, 64);
    if (lane == 0) {
        const float invN = 1.0f / (16.0f * 3.0f * 512.0f * 512.0f);
        bool first = ((blockIdx.x | blockIdx.y | blockIdx.z) == 0) && (wv == 0);
        float contrib = fmaf(vsum, -invN, first ? 1.0f : 0.0f);
        atomicAdd(out, contrib);
    }
}

extern "C" void kernel_launch(void* const* d_in, const int* in_sizes, int n_in,
                              void* d_out, int out_size, void* d_ws, size_t ws_size,
                              hipStream_t stream) {
    const float* img1 = (const float*)d_in[0];
    const float* img2 = (const float*)d_in[1];
    const float* window = (const float*)d_in[2];
    float* out = (float*)d_out;

    // out[0] = 0.0f (bit pattern 0x00000000 IS memset-able); waves accumulate
    // 1 - sum*invN directly. d_ws intentionally unused -> its poison is harmless.
    hipMemsetAsync(out, 0, sizeof(float), stream);

    dim3 block(128);
    dim3 grid(8, 16, 48);                           // 6144 blocks, 2 waves each
    ssim_kernel<<<grid, block, 0, stream>>>(img1, img2, window, out);
}

// Round 10
// 144.605 us; speedup vs baseline: 1.8109x; 1.8109x over previous
//
#include <hip/hip_runtime.h>

typedef _Float16 f16;
typedef __fp16 fp16x2 __attribute__((ext_vector_type(2)));
typedef _Float16 half4 __attribute__((ext_vector_type(4)));
typedef _Float16 half8 __attribute__((ext_vector_type(8)));
typedef float floatx16 __attribute__((ext_vector_type(16)));

#define FSTR 44     // r-dim per field in f16 (42 used; reads of r44..47 hit next field / pad, coeff g=0)
#define XSTR 180    // per-x stride f16: 4*44 + 4 pad = 360 B; 90 dwords (=26 mod 32) -> conflict-free
#define WTOT (32 * XSTR)          // 5760 f16 = 11520 B per wave; 2 waves = 23040 B

union H8 { half8 v; half4 h[2]; fp16x2 p[4]; unsigned u[4]; };
union H4 { half4 v; fp16x2 p[2]; };

// Fused SSIM via MFMA, H-pass then V-pass, per-wave private T^T in LDS.
// BYTE-EXACT ROUND-3 BODY AND TAIL (verified best: 53.5 us kernel, 384 KB
// writes = spill-free, e2e 146). ONE token changed: __launch_bounds__(128,2).
// Rationale: every no-spill variant measures Occ ~25% = 2 waves/SIMD, i.e. the
// unified VGPR+AGPR granule already exceeds 170 (84 arch + ~128 AGPR from the
// scheduler overlapping accT/accU lifetimes). So (128,3) buys NO occupancy but
// still squeezes the VGPR side. (128,2) = cap 256: same occupancy by
// construction (floor already paid), +86 regs of legal headroom for load ILP,
// zero spill pressure. Worst case neutral.
// MEASURED CONSTRAINTS (each cost a round, do not violate):
//  - EXACT r3 body/ordering. r8 accR-reuse+sched_barrier: 21.9 MB spill.
//    r6 band2-late: 24 MB spill. r4 reg-resident pass2 / r5 2-tile loop:
//    28-65 MB spill (compile-time loops fully unroll at -O3, merge lifetimes).
//  - Tail = 48 PADDED per-slice buckets + tiny finalize dispatch. r9's single
//    out[0] atomic: 12288 same-line RMWs serialize -> +128 us. Spread lines.
//  - NO XCD swizzle: r7 isolated it: FETCH 92->49 MB but dur 53.5->62 us
//    (latency-bound; same-row concentration costs more than locality buys).
//  - No fences in tail: agent-scope fence = L2 writeback on gfx950 (8x, r1).
//  - m=1 source rows deduped at oy+36: T rows >=42 multiply g=0.
// No clip: |clip(x)-x| <= 1e-6, ~500x below fp16-RTZ noise already present.

__device__ __forceinline__ void load_tile(
    const float* __restrict__ img1, const float* __restrict__ img2, size_t base,
    int row, int rowcap, int x0, int q, float4 ra[3][2], float4 rb[3][2], unsigned mk[3])
{
    int rowc = min(max(min(row, rowcap), 0), 511);   // load address (deduped)
    bool rok = (row >= 0) && (row <= 511);           // mask from wanted row
    const float* r1 = img1 + base + (size_t)rowc * 512;
    const float* r2 = img2 + base + (size_t)rowc * 512;
    #pragma unroll
    for (int ch = 0; ch < 3; ++ch) {
        int cb  = x0 - 8 + 16 * ch + 8 * q;      // 8-col chunk, 32B aligned
        int cbc = min(max(cb, 0), 504);
        mk[ch] = (cb == cbc && rok) ? 0xFFFFFFFFu : 0u;
        ra[ch][0] = *(const float4*)(r1 + cbc);
        ra[ch][1] = *(const float4*)(r1 + cbc + 4);
        rb[ch][0] = *(const float4*)(r2 + cbc);
        rb[ch][1] = *(const float4*)(r2 + cbc + 4);
    }
}

__device__ __forceinline__ void compute_acct(
    const float4 ra[3][2], const float4 rb[3][2], const unsigned mk[3],
    const half8 band1[3], floatx16 acc[4])
{
    #pragma unroll
    for (int ch = 0; ch < 3; ++ch) {
        H8 F0, F1, F2, F3;
        #pragma unroll
        for (int h = 0; h < 2; ++h) {
            const float as[4] = {ra[ch][h].x, ra[ch][h].y, ra[ch][h].z, ra[ch][h].w};
            const float bs[4] = {rb[ch][h].x, rb[ch][h].y, rb[ch][h].z, rb[ch][h].w};
            #pragma unroll
            for (int t = 0; t < 2; ++t) {
                float a0 = as[2*t], a1 = as[2*t+1];
                float b0 = bs[2*t], b1 = bs[2*t+1];
                int jj = 2 * h + t;
                F0.p[jj] = __builtin_amdgcn_cvt_pkrtz(a0, a1);
                F1.p[jj] = __builtin_amdgcn_cvt_pkrtz(b0, b1);
                F2.p[jj] = __builtin_amdgcn_cvt_pkrtz(a0*a0 + b0*b0, a1*a1 + b1*b1);
                F3.p[jj] = __builtin_amdgcn_cvt_pkrtz(a0*b0, a1*b1);
            }
        }
        // OOB mask (row clamp / col chunk) as packed AND: {0,1} multiply -> bitmask
        unsigned m = mk[ch];
        #pragma unroll
        for (int i = 0; i < 4; ++i) { F0.u[i] &= m; F1.u[i] &= m; F2.u[i] &= m; F3.u[i] &= m; }
        acc[0] = __builtin_amdgcn_mfma_f32_32x32x16_f16(F0.v, band1[ch], acc[0], 0, 0, 0);
        acc[1] = __builtin_amdgcn_mfma_f32_32x32x16_f16(F1.v, band1[ch], acc[1], 0, 0, 0);
        acc[2] = __builtin_amdgcn_mfma_f32_32x32x16_f16(F2.v, band1[ch], acc[2], 0, 0, 0);
        acc[3] = __builtin_amdgcn_mfma_f32_32x32x16_f16(F3.v, band1[ch], acc[3], 0, 0, 0);
    }
}

// write T^T fields [FLO,FHI) of m-tile MT; D: row r = 8s+4q(+32*MT), col x = ln.
// MT==1,s==1,q==1 would be r44..47 (overlaps next field's r0..3) -> exec-masked off;
// those slots are only ever read against g=0.
template<int MT, int FLO, int FHI>
__device__ __forceinline__ void write_T(f16* tx, int q, const floatx16 acc[4])
{
    #pragma unroll
    for (int f = FLO; f < FHI; ++f) {
        #pragma unroll
        for (int s = 0; s < (MT == 0 ? 4 : 2); ++s) {
            const int r0 = 8 * s + 4 * q + 32 * MT;
            H4 h4;
            h4.p[0] = __builtin_amdgcn_cvt_pkrtz(acc[f][4*s],   acc[f][4*s+1]);
            h4.p[1] = __builtin_amdgcn_cvt_pkrtz(acc[f][4*s+2], acc[f][4*s+3]);
            if (MT == 1 && s == 1) {
                if (q == 0) *(half4*)(tx + f * FSTR + r0) = h4.v;
            } else {
                *(half4*)(tx + f * FSTR + r0) = h4.v;
            }
        }
    }
}

__global__ __launch_bounds__(128, 2) void ssim_kernel(
    const float* __restrict__ img1, const float* __restrict__ img2,
    const float* __restrict__ window, float* __restrict__ acc)
{
    __shared__ __align__(16) f16 smem[2 * WTOT];

    const int tid  = threadIdx.x;
    const int lane = tid & 63;
    const int wv   = tid >> 6;
    const int q    = lane >> 5;
    const int ln   = lane & 31;

    const int bz = blockIdx.z;
    const int c  = bz % 3;
    const int x0 = blockIdx.x * 64 + 32 * wv;
    const int oy = blockIdx.y * 32;
    const size_t base = (size_t)bz * (512 * 512);

    f16* Tw = smem + wv * WTOT;                    // this wave's T^T [x32][f4][r44] (+4 pad)

    // ---- issue ALL 24 float4 loads up front (both m-tiles in flight) ----
    float4 ra[3][2], rb[3][2]; unsigned mk[3];
    load_tile(img1, img2, base, oy - 5 + ln, 511, x0, q, ra, rb, mk);
    float4 ra1[3][2], rb1[3][2]; unsigned mk1[3];
    load_tile(img1, img2, base, oy + 27 + ln, oy + 36, x0, q, ra1, rb1, mk1);

    // per-wave 1-D gaussian: lane t<11 holds g[t] = sum_j w2d[t][j]
    float gv = 0.f;
    if (lane < 11) {
        const float* w2 = window + c * 121 + lane * 11;
        #pragma unroll
        for (int j = 0; j < 11; ++j) gv += w2[j];
    }

    // zero each x-slot's 4-f16 pad (read x g=0 by pass2; must be finite)
    if (lane < 32) {
        half4 z4 = {};
        *(half4*)(Tw + lane * XSTR + 176) = z4;
    }

    // bands from ONE shared 11-shuffle gather per ch:
    //   band1[j] = g[16ch+8q-ln-3 + j], band2[j] = band-gather[j+3]
    half8 band1[3], band2[3];
    #pragma unroll
    for (int ch = 0; ch < 3; ++ch) {
        int ib = 16 * ch + 8 * q - ln - 3;
        float gg[11];
        #pragma unroll
        for (int t = 0; t < 11; ++t) gg[t] = __shfl(gv, (ib + t) & 63, 64);
        H8 t1, t2;
        #pragma unroll
        for (int jj = 0; jj < 4; ++jj) {
            fp16x2 p1 = { (__fp16)gg[2*jj],     (__fp16)gg[2*jj + 1] };
            fp16x2 p2 = { (__fp16)gg[2*jj + 3], (__fp16)gg[2*jj + 4] };
            t1.p[jj] = p1; t2.p[jj] = p2;
        }
        band1[ch] = t1.v; band2[ch] = t2.v;
    }

    // ---- pass 1, m=0 (rows oy-5+ln) ----
    floatx16 accT[4] = {};
    compute_acct(ra, rb, mk, band1, accT);
    f16* tx = Tw + ln * XSTR;
    write_T<0, 0, 4>(tx, q, accT);

    // ---- pass 1, m=1 (rows oy+27+ln, deduped source; only r32..43 stored) ----
    floatx16 accU[4] = {};
    compute_acct(ra1, rb1, mk1, band1, accU);
    write_T<1, 0, 4>(tx, q, accU);

    // ---- pass 2 (vertical): A-frags = two aligned b64 LDS reads per (ch,f) ----
    // No barrier needed: Tw is wave-private, DS ops ordered in-wave via lgkmcnt.
    floatx16 accH[4] = {};
    #pragma unroll
    for (int ch = 0; ch < 3; ++ch) {
        const f16* tb = Tw + ln * XSTR + 16 * ch + 8 * q;
        #pragma unroll
        for (int f = 0; f < 4; ++f) {
            H8 af;
            af.h[0] = *(const half4*)(tb + f * FSTR);
            af.h[1] = *(const half4*)(tb + f * FSTR + 4);
            accH[f] = __builtin_amdgcn_mfma_f32_32x32x16_f16(af.v, band2[ch], accH[f], 0, 0, 0);
        }
    }

    // ---- epilogue: all 16 outputs per lane valid (exact tiling) ----
    float vsum = 0.f;
    const float C1 = 1e-4f, C2 = 9e-4f;
    #pragma unroll
    for (int r = 0; r < 16; ++r) {
        float mu1 = accH[0][r], mu2 = accH[1][r];
        float S = accH[2][r], E12 = accH[3][r];
        float mu11 = mu1 * mu1, mu22 = mu2 * mu2, mu12 = mu1 * mu2;
        float num = (2.f * mu12 + C1) * (2.f * (E12 - mu12) + C2);
        float den = (mu11 + mu22 + C1) * (S - mu11 - mu22 + C2);
        vsum += num * __builtin_amdgcn_rcpf(den);
    }

    // wave reduce -> ONE fire-and-forget atomic per wave, padded per-slice bucket
    #pragma unroll
    for (int off = 32; off > 0; off >>= 1) vsum += __shfl_down(vsum, off, 64);
    if (lane == 0) atomicAdd(&acc[bz * 16], vsum);   // 256 adds/bucket, 48 cachelines
}

__global__ void ssim_finalize(const float* __restrict__ acc,
                              float* __restrict__ out, float invN)
{
    const int lane = threadIdx.x;
    float v = (lane < 48) ? acc[lane * 16] : 0.f;
    #pragma unroll
    for (int off = 32; off > 0; off >>= 1) v += __shfl_down(v, off, 64);
    if (lane == 0) out[0] = 1.0f - v * invN;
}

extern "C" void kernel_launch(void* const* d_in, const int* in_sizes, int n_in,
                              void* d_out, int out_size, void* d_ws, size_t ws_size,
                              hipStream_t stream) {
    const float* img1 = (const float*)d_in[0];
    const float* img2 = (const float*)d_in[1];
    const float* window = (const float*)d_in[2];
    float* out = (float*)d_out;
    float* acc = (float*)d_ws;                      // 48 buckets, stride 16 f32 (64 B)

    const float invN = 1.0f / (16.0f * 3.0f * 512.0f * 512.0f);

    // d_ws is poisoned (0xAA) before every call: zero the buckets
    hipMemsetAsync(acc, 0, 48 * 16 * sizeof(float), stream);

    dim3 block(128);
    dim3 grid(8, 16, 48);                           // 6144 blocks, 2 waves each
    ssim_kernel<<<grid, block, 0, stream>>>(img1, img2, window, acc);
    ssim_finalize<<<1, 64, 0, stream>>>(acc, out, invN);
}